// Round 1
// baseline (329.381 us; speedup 1.0000x reference)
//
#include <hip/hip_runtime.h>

typedef __bf16 bf16_t;
typedef __bf16 bf16x8 __attribute__((ext_vector_type(8)));
typedef __bf16 bf16x4 __attribute__((ext_vector_type(4)));
typedef float  f32x4  __attribute__((ext_vector_type(4)));

// ---------------------------------------------------------------------------
// Workspace layout (floats unless noted):
//   A  : [4096][256] f32   (xf @ W1[0:26])                       4 MB
//   C  : [4096][256] f32   (xf @ W1[26:52] + qst @ W1[52:180] + b1)  4 MB
//   Wt : 3 x [256][256] bf16, g2/g3/g4 weights transposed [out][in]  384 KB
//   xg : [64][256] f32     (pair-summed g output)                64 KB
// ---------------------------------------------------------------------------

// swizzled LDS column index: 16B-block XOR on row low bits -> conflict-free
// ds_read_b128 A-fragment reads with zero padding (stays at exactly 64 KB).
__device__ __forceinline__ int swz(int row, int col) {
  return (((col >> 3) ^ (row & 7)) << 3) | (col & 7);
}

// ---------------- prep: A, C, weight transpose+cast, zero xg ----------------
__global__ __launch_bounds__(256) void rn_prep_kernel(
    const float* __restrict__ x, const float* __restrict__ qst,
    const float* __restrict__ g1w, const float* __restrict__ g1b,
    const float* __restrict__ g2w, const float* __restrict__ g3w,
    const float* __restrict__ g4w,
    float* __restrict__ A, float* __restrict__ C,
    bf16_t* __restrict__ Wt, float* __restrict__ xg)
{
  int blk = blockIdx.x;
  int n   = threadIdx.x;  // 0..255
  if (blk < 256) {
    // block = (b, jg): rows jg*16 .. jg*16+15 of batch b; thread = output col n
    int b  = blk >> 2;
    int jg = (blk & 3) * 16;
    // qst part (independent of row): accQ = b1[n] + sum_q qst[b,q]*W1[52+q, n]
    float accQ = g1b[n];
    const float* qb = qst + b * 128;
    #pragma unroll 8
    for (int qi = 0; qi < 128; ++qi)
      accQ += qb[qi] * g1w[(52 + qi) * 256 + n];

    float w24 = g1w[24 * 256 + n], w25 = g1w[25 * 256 + n];
    float w50 = g1w[50 * 256 + n], w51 = g1w[51 * 256 + n];
    float accA[16], accC[16];
    #pragma unroll
    for (int t = 0; t < 16; ++t) {
      int j = jg + t;
      // faithful to (a/d - d/2)/(d/2.0) float arithmetic, d=8 (exact pow2 ops)
      float cx = ((float)j * 0.125f - 4.0f) * 0.25f;
      float cy = ((float)(j & 7) - 4.0f) * 0.25f;
      accA[t] = cx * w24 + cy * w25;
      accC[t] = accQ + cx * w50 + cy * w51;
    }
    for (int c = 0; c < 24; ++c) {
      float wa = g1w[c * 256 + n];
      float wc = g1w[(26 + c) * 256 + n];
      const float* xc = x + (b * 24 + c) * 64 + jg;
      #pragma unroll
      for (int t = 0; t < 16; ++t) {
        float xv = xc[t];   // uniform per thread -> scalar load
        accA[t] += xv * wa;
        accC[t] += xv * wc;
      }
    }
    #pragma unroll
    for (int t = 0; t < 16; ++t) {
      A[(b * 64 + jg + t) * 256 + n] = accA[t];
      C[(b * 64 + jg + t) * 256 + n] = accC[t];
    }
  } else if (blk < 256 + 768) {
    // transpose g2/g3/g4 [in][out] -> bf16 [out][in]
    int idx = (blk - 256) * 256 + n;       // 0..196607
    int mat = idx >> 16;
    int e   = idx & 65535;
    int k   = e & 255;        // input dim (fastest -> coalesced writes)
    int no  = e >> 8;         // output dim
    const float* W = (mat == 0) ? g2w : (mat == 1 ? g3w : g4w);
    Wt[mat * 65536 + no * 256 + k] = (bf16_t)W[k * 256 + no];
  } else {
    int idx = (blk - (256 + 768)) * 256 + n;  // 64 blocks -> 16384
    xg[idx] = 0.f;
  }
}

// ---------------- main fused g-MLP (layers 2..4) + pair sum ----------------
// one block per (b, i): M = 64 rows (j), N = K = 256.
// wave w owns output columns [w*64, w*64+64).
__global__ __launch_bounds__(256) void rn_main_kernel(
    const float* __restrict__ A, const float* __restrict__ C,
    const bf16_t* __restrict__ Wt,
    const float* __restrict__ g2b, const float* __restrict__ g3b,
    const float* __restrict__ g4b,
    float* __restrict__ xg)
{
  __shared__ bf16_t hbuf[2][64][256];   // exactly 64 KB, XOR-swizzled cols

  int tid  = threadIdx.x;
  int bx   = blockIdx.x;
  int b    = bx >> 6;
  int lane = tid & 63;
  int wave = tid >> 6;
  int n0   = wave * 64;

  // ---- build h1 = relu(A[b,j,:] + C[b,i,:]) into hbuf[0] ----
  {
    const float* Crow = C + (size_t)bx * 256;        // row (b*64 + i)
    const float* Ab   = A + (size_t)b * 64 * 256;
    #pragma unroll
    for (int it = 0; it < 16; ++it) {
      int g = it * 256 + tid;
      int j = g >> 6;
      int n = (g & 63) * 4;
      const float4 a4 = *(const float4*)(Ab + j * 256 + n);
      const float4 c4 = *(const float4*)(Crow + n);
      bf16x4 v;
      v[0] = (bf16_t)fmaxf(a4.x + c4.x, 0.f);
      v[1] = (bf16_t)fmaxf(a4.y + c4.y, 0.f);
      v[2] = (bf16_t)fmaxf(a4.z + c4.z, 0.f);
      v[3] = (bf16_t)fmaxf(a4.w + c4.w, 0.f);
      *(bf16x4*)&hbuf[0][j][swz(j, n)] = v;
    }
  }

  const float* biases[3] = {g2b, g3b, g4b};
  int r = lane & 15;     // MFMA: A-row / B-col / D-col within 16x16 tile
  int q = lane >> 4;     // quad: k-chunk selector / D-row group
  int bufin = 0;

  for (int L = 0; L < 3; ++L) {
    __syncthreads();
    const bf16_t* W = Wt + L * 65536;
    const float* bias = biases[L];

    f32x4 acc[4][4];
    #pragma unroll
    for (int mt = 0; mt < 4; ++mt)
      #pragma unroll
      for (int nt = 0; nt < 4; ++nt)
        #pragma unroll
        for (int e = 0; e < 4; ++e) acc[mt][nt][e] = 0.f;

    #pragma unroll
    for (int ks = 0; ks < 8; ++ks) {
      int k0 = ks * 32 + q * 8;    // this lane's 8-element k-run
      bf16x8 a[4], bb[4];
      #pragma unroll
      for (int mt = 0; mt < 4; ++mt) {
        int row = mt * 16 + r;
        a[mt] = *(const bf16x8*)&hbuf[bufin][row][swz(row, k0)];
      }
      #pragma unroll
      for (int nt = 0; nt < 4; ++nt)
        bb[nt] = *(const bf16x8*)&W[(n0 + nt * 16 + r) * 256 + k0];
      #pragma unroll
      for (int mt = 0; mt < 4; ++mt)
        #pragma unroll
        for (int nt = 0; nt < 4; ++nt)
          acc[mt][nt] = __builtin_amdgcn_mfma_f32_16x16x32_bf16(
              a[mt], bb[nt], acc[mt][nt], 0, 0, 0);
    }

    float bv[4];
    #pragma unroll
    for (int nt = 0; nt < 4; ++nt) bv[nt] = bias[n0 + nt * 16 + r];

    if (L < 2) {
      int bo = bufin ^ 1;
      #pragma unroll
      for (int mt = 0; mt < 4; ++mt)
        #pragma unroll
        for (int nt = 0; nt < 4; ++nt) {
          int col = n0 + nt * 16 + r;
          #pragma unroll
          for (int rg = 0; rg < 4; ++rg) {
            int row = mt * 16 + q * 4 + rg;   // D layout: row = quad*4 + reg
            hbuf[bo][row][swz(row, col)] =
                (bf16_t)fmaxf(acc[mt][nt][rg] + bv[nt], 0.f);
          }
        }
      bufin = bo;
    } else {
      // last layer: bias+relu in fp32, reduce over all 64 rows, atomic to xg
      #pragma unroll
      for (int nt = 0; nt < 4; ++nt) {
        float s = 0.f;
        #pragma unroll
        for (int mt = 0; mt < 4; ++mt)
          #pragma unroll
          for (int rg = 0; rg < 4; ++rg)
            s += fmaxf(acc[mt][nt][rg] + bv[nt], 0.f);
        s += __shfl_xor(s, 16, 64);
        s += __shfl_xor(s, 32, 64);
        if (q == 0) atomicAdd(&xg[b * 256 + n0 + nt * 16 + r], s);
      }
    }
  }
}

// ---------------- f-MLP + log_softmax (tiny, fp32) ----------------
__global__ __launch_bounds__(256) void rn_f_kernel(
    const float* __restrict__ xg,
    const float* __restrict__ f1w, const float* __restrict__ f1b,
    const float* __restrict__ f2w, const float* __restrict__ f2b,
    const float* __restrict__ f3w, const float* __restrict__ f3b,
    float* __restrict__ out)
{
  __shared__ float xs[256], t1[256], t2[256], lg[28], lse[1];
  int b = blockIdx.x, tid = threadIdx.x;
  xs[tid] = xg[b * 256 + tid];
  __syncthreads();
  float acc = f1b[tid];
  for (int k = 0; k < 256; ++k) acc += xs[k] * f1w[k * 256 + tid];
  t1[tid] = fmaxf(acc, 0.f);
  __syncthreads();
  acc = f2b[tid];
  for (int k = 0; k < 256; ++k) acc += t1[k] * f2w[k * 256 + tid];
  t2[tid] = fmaxf(acc, 0.f);
  __syncthreads();
  if (tid < 28) {
    float a2 = f3b[tid];
    for (int k = 0; k < 256; ++k) a2 += t2[k] * f3w[k * 28 + tid];
    lg[tid] = a2;
  }
  __syncthreads();
  if (tid == 0) {
    float m = lg[0];
    for (int j = 1; j < 28; ++j) m = fmaxf(m, lg[j]);
    float se = 0.f;
    for (int j = 0; j < 28; ++j) se += expf(lg[j] - m);
    lse[0] = m + logf(se);
  }
  __syncthreads();
  if (tid < 28) out[b * 28 + tid] = lg[tid] - lse[0];
}

// ---------------------------------------------------------------------------
extern "C" void kernel_launch(void* const* d_in, const int* in_sizes, int n_in,
                              void* d_out, int out_size, void* d_ws, size_t ws_size,
                              hipStream_t stream) {
  (void)in_sizes; (void)n_in; (void)out_size; (void)ws_size;
  const float* x   = (const float*)d_in[0];
  const float* qst = (const float*)d_in[1];
  const float* g1w = (const float*)d_in[2];
  const float* g1b = (const float*)d_in[3];
  const float* g2w = (const float*)d_in[4];
  const float* g2b = (const float*)d_in[5];
  const float* g3w = (const float*)d_in[6];
  const float* g3b = (const float*)d_in[7];
  const float* g4w = (const float*)d_in[8];
  const float* g4b = (const float*)d_in[9];
  const float* f1w = (const float*)d_in[10];
  const float* f1b = (const float*)d_in[11];
  const float* f2w = (const float*)d_in[12];
  const float* f2b = (const float*)d_in[13];
  const float* f3w = (const float*)d_in[14];
  const float* f3b = (const float*)d_in[15];
  float* out = (float*)d_out;

  float*  A  = (float*)d_ws;
  float*  C  = A + 4096 * 256;
  bf16_t* Wt = (bf16_t*)(C + 4096 * 256);
  float*  xg = (float*)((char*)Wt + 3 * 65536 * sizeof(bf16_t));

  rn_prep_kernel<<<256 + 768 + 64, 256, 0, stream>>>(
      x, qst, g1w, g1b, g2w, g3w, g4w, A, C, Wt, xg);
  rn_main_kernel<<<4096, 256, 0, stream>>>(A, C, Wt, g2b, g3b, g4b, xg);
  rn_f_kernel<<<64, 256, 0, stream>>>(xg, f1w, f1b, f2w, f2b, f3w, f3b, out);
}

// Round 2
// 317.560 us; speedup vs baseline: 1.0372x; 1.0372x over previous
//
#include <hip/hip_runtime.h>

typedef __bf16 bf16_t;
typedef __bf16 bf16x8 __attribute__((ext_vector_type(8)));
typedef __bf16 bf16x4 __attribute__((ext_vector_type(4)));
typedef float  f32x4  __attribute__((ext_vector_type(4)));

// ---------------------------------------------------------------------------
// Workspace layout (floats unless noted):
//   A  : [4096][256] f32   (xf @ W1[0:26])                       4 MB
//   C  : [4096][256] f32   (xf @ W1[26:52] + qst @ W1[52:180] + b1)  4 MB
//   Wt : 3 x [256][256] bf16, g2/g3/g4 weights transposed [out][in]  384 KB
//   xg : [64][256] f32     (pair-summed g output)                64 KB
// ---------------------------------------------------------------------------

// swizzled LDS column index: 16B-block XOR on row low bits -> conflict-free
// ds_read_b128 A-fragment reads with zero padding (stays at exactly 32 KB).
__device__ __forceinline__ int swz(int row, int col) {
  return (((col >> 3) ^ (row & 7)) << 3) | (col & 7);
}

// ---------------- prep: A, C, weight transpose+cast, zero xg ----------------
__global__ __launch_bounds__(256) void rn_prep_kernel(
    const float* __restrict__ x, const float* __restrict__ qst,
    const float* __restrict__ g1w, const float* __restrict__ g1b,
    const float* __restrict__ g2w, const float* __restrict__ g3w,
    const float* __restrict__ g4w,
    float* __restrict__ A, float* __restrict__ C,
    bf16_t* __restrict__ Wt, float* __restrict__ xg)
{
  int blk = blockIdx.x;
  int n   = threadIdx.x;  // 0..255
  if (blk < 256) {
    // block = (b, jg): rows jg*16 .. jg*16+15 of batch b; thread = output col n
    int b  = blk >> 2;
    int jg = (blk & 3) * 16;
    // qst part (independent of row): accQ = b1[n] + sum_q qst[b,q]*W1[52+q, n]
    float accQ = g1b[n];
    const float* qb = qst + b * 128;
    #pragma unroll 8
    for (int qi = 0; qi < 128; ++qi)
      accQ += qb[qi] * g1w[(52 + qi) * 256 + n];

    float w24 = g1w[24 * 256 + n], w25 = g1w[25 * 256 + n];
    float w50 = g1w[50 * 256 + n], w51 = g1w[51 * 256 + n];
    float accA[16], accC[16];
    #pragma unroll
    for (int t = 0; t < 16; ++t) {
      int j = jg + t;
      // faithful to (a/d - d/2)/(d/2.0) float arithmetic, d=8 (exact pow2 ops)
      float cx = ((float)j * 0.125f - 4.0f) * 0.25f;
      float cy = ((float)(j & 7) - 4.0f) * 0.25f;
      accA[t] = cx * w24 + cy * w25;
      accC[t] = accQ + cx * w50 + cy * w51;
    }
    for (int c = 0; c < 24; ++c) {
      float wa = g1w[c * 256 + n];
      float wc = g1w[(26 + c) * 256 + n];
      const float* xc = x + (b * 24 + c) * 64 + jg;
      #pragma unroll
      for (int t = 0; t < 16; ++t) {
        float xv = xc[t];   // uniform per thread -> scalar load
        accA[t] += xv * wa;
        accC[t] += xv * wc;
      }
    }
    #pragma unroll
    for (int t = 0; t < 16; ++t) {
      A[(b * 64 + jg + t) * 256 + n] = accA[t];
      C[(b * 64 + jg + t) * 256 + n] = accC[t];
    }
  } else if (blk < 256 + 768) {
    // transpose g2/g3/g4 [in][out] -> bf16 [out][in]
    int idx = (blk - 256) * 256 + n;       // 0..196607
    int mat = idx >> 16;
    int e   = idx & 65535;
    int k   = e & 255;        // input dim (fastest -> coalesced writes)
    int no  = e >> 8;         // output dim
    const float* W = (mat == 0) ? g2w : (mat == 1 ? g3w : g4w);
    Wt[mat * 65536 + no * 256 + k] = (bf16_t)W[k * 256 + no];
  } else {
    int idx = (blk - (256 + 768)) * 256 + n;  // 64 blocks -> 16384
    xg[idx] = 0.f;
  }
}

// ---------------- main fused g-MLP (layers 2..4) + pair sum ----------------
// one block per (b, i): M = 64 rows (j), N = K = 256.
// wave w owns output columns [w*64, w*64+64).
// SINGLE 32 KB h buffer: all LDS reads of a layer finish before the epilogue
// writes start (extra __syncthreads between phases) -> 2x blocks/CU vs dbuf.
__global__ __launch_bounds__(256, 4) void rn_main_kernel(
    const float* __restrict__ A, const float* __restrict__ C,
    const bf16_t* __restrict__ Wt,
    const float* __restrict__ g2b, const float* __restrict__ g3b,
    const float* __restrict__ g4b,
    float* __restrict__ xg)
{
  __shared__ bf16_t hbuf[64][256];   // exactly 32 KB, XOR-swizzled cols

  int tid  = threadIdx.x;
  int bx   = blockIdx.x;
  int b    = bx >> 6;
  int lane = tid & 63;
  int wave = tid >> 6;
  int n0   = wave * 64;

  // ---- build h1 = relu(A[b,j,:] + C[b,i,:]) into hbuf ----
  {
    const float* Crow = C + (size_t)bx * 256;        // row (b*64 + i)
    const float* Ab   = A + (size_t)b * 64 * 256;
    #pragma unroll
    for (int it = 0; it < 16; ++it) {
      int g = it * 256 + tid;
      int j = g >> 6;
      int n = (g & 63) * 4;
      const float4 a4 = *(const float4*)(Ab + j * 256 + n);
      const float4 c4 = *(const float4*)(Crow + n);
      bf16x4 v;
      v[0] = (bf16_t)fmaxf(a4.x + c4.x, 0.f);
      v[1] = (bf16_t)fmaxf(a4.y + c4.y, 0.f);
      v[2] = (bf16_t)fmaxf(a4.z + c4.z, 0.f);
      v[3] = (bf16_t)fmaxf(a4.w + c4.w, 0.f);
      *(bf16x4*)&hbuf[j][swz(j, n)] = v;
    }
  }

  const float* biases[3] = {g2b, g3b, g4b};
  int r = lane & 15;     // MFMA: A-row / B-col / D-col within 16x16 tile
  int q = lane >> 4;     // quad: k-chunk selector / D-row group

  for (int L = 0; L < 3; ++L) {
    __syncthreads();     // h (writes from previous phase) ready for reads
    const bf16_t* W = Wt + L * 65536;
    const float* bias = biases[L];

    f32x4 acc[4][4];
    #pragma unroll
    for (int mt = 0; mt < 4; ++mt)
      #pragma unroll
      for (int nt = 0; nt < 4; ++nt)
        #pragma unroll
        for (int e = 0; e < 4; ++e) acc[mt][nt][e] = 0.f;

    #pragma unroll
    for (int ks = 0; ks < 8; ++ks) {
      int k0 = ks * 32 + q * 8;    // this lane's 8-element k-run
      bf16x8 a[4], bb[4];
      #pragma unroll
      for (int mt = 0; mt < 4; ++mt) {
        int row = mt * 16 + r;
        a[mt] = *(const bf16x8*)&hbuf[row][swz(row, k0)];
      }
      #pragma unroll
      for (int nt = 0; nt < 4; ++nt)
        bb[nt] = *(const bf16x8*)&W[(n0 + nt * 16 + r) * 256 + k0];
      #pragma unroll
      for (int mt = 0; mt < 4; ++mt)
        #pragma unroll
        for (int nt = 0; nt < 4; ++nt)
          acc[mt][nt] = __builtin_amdgcn_mfma_f32_16x16x32_bf16(
              a[mt], bb[nt], acc[mt][nt], 0, 0, 0);
    }

    float bv[4];
    #pragma unroll
    for (int nt = 0; nt < 4; ++nt) bv[nt] = bias[n0 + nt * 16 + r];

    if (L < 2) {
      __syncthreads();   // all reads of hbuf done -> safe to overwrite
      #pragma unroll
      for (int mt = 0; mt < 4; ++mt)
        #pragma unroll
        for (int nt = 0; nt < 4; ++nt) {
          int col = n0 + nt * 16 + r;
          #pragma unroll
          for (int rg = 0; rg < 4; ++rg) {
            int row = mt * 16 + q * 4 + rg;   // D layout: row = quad*4 + reg
            hbuf[row][swz(row, col)] =
                (bf16_t)fmaxf(acc[mt][nt][rg] + bv[nt], 0.f);
          }
        }
    } else {
      // last layer: bias+relu in fp32, reduce over all 64 rows, atomic to xg
      #pragma unroll
      for (int nt = 0; nt < 4; ++nt) {
        float s = 0.f;
        #pragma unroll
        for (int mt = 0; mt < 4; ++mt)
          #pragma unroll
          for (int rg = 0; rg < 4; ++rg)
            s += fmaxf(acc[mt][nt][rg] + bv[nt], 0.f);
        s += __shfl_xor(s, 16, 64);
        s += __shfl_xor(s, 32, 64);
        if (q == 0) atomicAdd(&xg[b * 256 + n0 + nt * 16 + r], s);
      }
    }
  }
}

// ---------------- f-MLP + log_softmax (tiny, fp32) ----------------
__global__ __launch_bounds__(256) void rn_f_kernel(
    const float* __restrict__ xg,
    const float* __restrict__ f1w, const float* __restrict__ f1b,
    const float* __restrict__ f2w, const float* __restrict__ f2b,
    const float* __restrict__ f3w, const float* __restrict__ f3b,
    float* __restrict__ out)
{
  __shared__ float xs[256], t1[256], t2[256], lg[28], lse[1];
  int b = blockIdx.x, tid = threadIdx.x;
  xs[tid] = xg[b * 256 + tid];
  __syncthreads();
  float acc = f1b[tid];
  for (int k = 0; k < 256; ++k) acc += xs[k] * f1w[k * 256 + tid];
  t1[tid] = fmaxf(acc, 0.f);
  __syncthreads();
  acc = f2b[tid];
  for (int k = 0; k < 256; ++k) acc += t1[k] * f2w[k * 256 + tid];
  t2[tid] = fmaxf(acc, 0.f);
  __syncthreads();
  if (tid < 28) {
    float a2 = f3b[tid];
    for (int k = 0; k < 256; ++k) a2 += t2[k] * f3w[k * 28 + tid];
    lg[tid] = a2;
  }
  __syncthreads();
  if (tid == 0) {
    float m = lg[0];
    for (int j = 1; j < 28; ++j) m = fmaxf(m, lg[j]);
    float se = 0.f;
    for (int j = 0; j < 28; ++j) se += expf(lg[j] - m);
    lse[0] = m + logf(se);
  }
  __syncthreads();
  if (tid < 28) out[b * 28 + tid] = lg[tid] - lse[0];
}

// ---------------------------------------------------------------------------
extern "C" void kernel_launch(void* const* d_in, const int* in_sizes, int n_in,
                              void* d_out, int out_size, void* d_ws, size_t ws_size,
                              hipStream_t stream) {
  (void)in_sizes; (void)n_in; (void)out_size; (void)ws_size;
  const float* x   = (const float*)d_in[0];
  const float* qst = (const float*)d_in[1];
  const float* g1w = (const float*)d_in[2];
  const float* g1b = (const float*)d_in[3];
  const float* g2w = (const float*)d_in[4];
  const float* g2b = (const float*)d_in[5];
  const float* g3w = (const float*)d_in[6];
  const float* g3b = (const float*)d_in[7];
  const float* g4w = (const float*)d_in[8];
  const float* g4b = (const float*)d_in[9];
  const float* f1w = (const float*)d_in[10];
  const float* f1b = (const float*)d_in[11];
  const float* f2w = (const float*)d_in[12];
  const float* f2b = (const float*)d_in[13];
  const float* f3w = (const float*)d_in[14];
  const float* f3b = (const float*)d_in[15];
  float* out = (float*)d_out;

  float*  A  = (float*)d_ws;
  float*  C  = A + 4096 * 256;
  bf16_t* Wt = (bf16_t*)(C + 4096 * 256);
  float*  xg = (float*)((char*)Wt + 3 * 65536 * sizeof(bf16_t));

  rn_prep_kernel<<<256 + 768 + 64, 256, 0, stream>>>(
      x, qst, g1w, g1b, g2w, g3w, g4w, A, C, Wt, xg);
  rn_main_kernel<<<4096, 256, 0, stream>>>(A, C, Wt, g2b, g3b, g4b, xg);
  rn_f_kernel<<<64, 256, 0, stream>>>(xg, f1w, f1b, f2w, f2b, f3w, f3b, out);
}